// Round 5
// baseline (2239.914 us; speedup 1.0000x reference)
//
#include <hip/hip_runtime.h>
#include <stdint.h>
#include <stddef.h>

// Problem constants (fixed by the reference)
#define BB 64
#define TT 8192
#define CC 16
#define NBK 64     // backtrace blocks
#define KBK 128    // steps per backtrace block (NBK*KBK == TT)

static __device__ __forceinline__ float groupMax16(float v) {
    v = fmaxf(v, __shfl_xor(v, 1, 16));
    v = fmaxf(v, __shfl_xor(v, 2, 16));
    v = fmaxf(v, __shfl_xor(v, 4, 16));
    v = fmaxf(v, __shfl_xor(v, 8, 16));
    return v;
}
static __device__ __forceinline__ float groupSum16(float v) {
    v += __shfl_xor(v, 1, 16);
    v += __shfl_xor(v, 2, 16);
    v += __shfl_xor(v, 4, 16);
    v += __shfl_xor(v, 8, 16);
    return v;
}

// All-gather of one float across each 16-lane group: q[j] = v from lane j.
// Bit-identical to an LDS write+readback; single LDS-unit pass (ds_bpermute).
static __device__ __forceinline__ void bcast16(float v, float q[16]) {
#pragma unroll
    for (int j = 0; j < 16; ++j) q[j] = __shfl(v, j, 16);
}

struct MaxI { float v; int i; };
// argmax over 16 values, FIRST occurrence wins ties (matches jnp.argmax).
static __device__ __forceinline__ MaxI argmax16(const float s[16]) {
    float m1[8]; int i1[8];
#pragma unroll
    for (int j = 0; j < 8; ++j) {
        bool t = s[2*j] >= s[2*j+1];
        m1[j] = t ? s[2*j] : s[2*j+1];
        i1[j] = t ? 2*j : 2*j+1;
    }
    float m2[4]; int i2[4];
#pragma unroll
    for (int j = 0; j < 4; ++j) {
        bool t = m1[2*j] >= m1[2*j+1];
        m2[j] = t ? m1[2*j] : m1[2*j+1];
        i2[j] = t ? i1[2*j] : i1[2*j+1];
    }
    float m3[2]; int i3[2];
#pragma unroll
    for (int j = 0; j < 2; ++j) {
        bool t = m2[2*j] >= m2[2*j+1];
        m3[j] = t ? m2[2*j] : m2[2*j+1];
        i3[j] = t ? i2[2*j] : i2[2*j+1];
    }
    bool t = m3[0] >= m3[1];
    MaxI r; r.v = t ? m3[0] : m3[1]; r.i = t ? i3[0] : i3[1];
    return r;
}

// ---------------------------------------------------------------------------
// Kernel 1: emission log-probs.  LP[b][t][c] = raw lp (Viterbi uses this
// unshifted), M[b][t] = max_c lp (forward uses exp(lp - m) safely).
// ---------------------------------------------------------------------------
__global__ __launch_bounds__(256) void k_emis(
    const float* __restrict__ x, const float* __restrict__ mug,
    const float* __restrict__ sdg, float* __restrict__ LP, float* __restrict__ M)
{
    const int tid = threadIdx.x;
    const int c = tid & 15, tl = tid >> 4;
    const int b = blockIdx.x >> 9;                 // 512 blocks per b
    const int t = ((blockIdx.x & 511) << 4) + tl;

    const float mu0 = mug[c*6+0], mu1 = mug[c*6+1], mu2 = mug[c*6+2], mu3 = mug[c*6+3];
    const float s0 = fmaxf(sdg[c*6+0], 0.f) + 0.1f;
    const float s1 = fmaxf(sdg[c*6+1], 0.f) + 0.1f;
    const float s2 = fmaxf(sdg[c*6+2], 0.f) + 0.1f;
    const float s3 = fmaxf(sdg[c*6+3], 0.f) + 0.1f;

    const float* xp = x + ((size_t)b*TT + t)*6;
    const float x0 = xp[0], x1 = xp[1], x2 = xp[2], x3 = xp[3];
    const float z0 = (x0-mu0)/s0, z1 = (x1-mu1)/s1, z2 = (x2-mu2)/s2, z3 = (x3-mu3)/s3;
    const float HL2P = 0.91893853320467274178f; // 0.5*log(2*pi)
    float e0 = -0.5f*(z0*z0) - logf(s0) - HL2P;
    float e1 = -0.5f*(z1*z1) - logf(s1) - HL2P;
    float e2 = -0.5f*(z2*z2) - logf(s2) - HL2P;
    float e3 = -0.5f*(z3*z3) - logf(s3) - HL2P;
    float lp = ((e0+e1)+e2)+e3;
    float m = groupMax16(lp);
    LP[((size_t)b*TT + t)*16 + c] = lp;
    if (c == 0) M[(size_t)b*TT + t] = m;
}

// ---------------------------------------------------------------------------
// Kernel 2: sequential scans.  blocks 0..15: forward (logp_x);
// blocks 16..31: Viterbi (psi tables + last state).  One wave per block,
// 16 lanes per sequence (lane = state c), 4 sequences per wave.
// State exchange via __shfl all-gather (single LDS-unit pass; no __shared__).
// ---------------------------------------------------------------------------
__global__ __launch_bounds__(64) void k_chain(
    const float* __restrict__ lAg, const float* __restrict__ lpig,
    const float* __restrict__ LP, const float* __restrict__ M,
    float* __restrict__ outLogp, uint32_t* __restrict__ PSI, int* __restrict__ CL)
{
    const int tid = threadIdx.x;
    const int g = tid >> 4, c = tid & 15;
    const bool isF = blockIdx.x < 16;
    const int b = ((int)(blockIdx.x & 15))*4 + g;

    // log_softmax(log_A, axis=1): lane c holds column c, la[j] = logA[j][c]
    float la[16];
#pragma unroll
    for (int j = 0; j < 16; ++j) {
        float raw = lAg[j*16 + c];
        float mx = groupMax16(raw);
        float sh = raw - mx;
        float sm = groupSum16(expf(sh));
        la[j] = sh - logf(sm);
    }
    float lpi;
    {
        float raw = lpig[c];
        float mx = groupMax16(raw);
        float sh = raw - mx;
        float sm = groupSum16(expf(sh));
        lpi = sh - logf(sm);
    }

    const float* lpb = LP + ((size_t)b*TT)*16 + c;
    const float LOG2E = 1.44269504088896340736f;

    if (isF) {
        // ---- forward in linear space, renorm every 4 steps ----
        float Ac[16];
#pragma unroll
        for (int j = 0; j < 16; ++j) Ac[j] = expf(la[j]);
        const float* mb = M + (size_t)b*TT;
        double macc = 0.0, lacc = 0.0;  // sum of maxes; sum of log2(renorm scales)
        float q[16];                    // alpha_prev, replicated per lane

        auto fstep = [&](float lp, float m, bool renorm) {
            float p = exp2f((lp - m) * LOG2E);
            macc += (double)m;
            float a0 = q[0]*Ac[0];   a0 = fmaf(q[1],Ac[1],a0);   a0 = fmaf(q[2],Ac[2],a0);   a0 = fmaf(q[3],Ac[3],a0);
            float a1 = q[4]*Ac[4];   a1 = fmaf(q[5],Ac[5],a1);   a1 = fmaf(q[6],Ac[6],a1);   a1 = fmaf(q[7],Ac[7],a1);
            float a2 = q[8]*Ac[8];   a2 = fmaf(q[9],Ac[9],a2);   a2 = fmaf(q[10],Ac[10],a2); a2 = fmaf(q[11],Ac[11],a2);
            float a3 = q[12]*Ac[12]; a3 = fmaf(q[13],Ac[13],a3); a3 = fmaf(q[14],Ac[14],a3); a3 = fmaf(q[15],Ac[15],a3);
            float v = (a0 + a1) + (a2 + a3);
            if (renorm) {
                float S = ((q[0]+q[1])+(q[2]+q[3])) + ((q[4]+q[5])+(q[6]+q[7]))
                        + ((q[8]+q[9])+(q[10]+q[11])) + ((q[12]+q[13])+(q[14]+q[15]));
                lacc += (double)log2f(S);
                v *= __builtin_amdgcn_rcpf(S);
            }
            float av = p * v;
            bcast16(av, q);
        };

        { // t = 0
            float lp = lpb[0], m = mb[0];
            float p = exp2f((lp - m) * LOG2E);
            macc += (double)m;
            float av = p * expf(lpi);
            bcast16(av, q);
        }
        fstep(lpb[1*16], mb[1], false);
        fstep(lpb[2*16], mb[2], false);
        fstep(lpb[3*16], mb[3], false);

        float clp0 = lpb[4*16], clp1 = lpb[5*16], clp2 = lpb[6*16], clp3 = lpb[7*16];
        float cm0 = mb[4], cm1 = mb[5], cm2 = mb[6], cm3 = mb[7];
        for (int t4 = 1; t4 < 2048; ++t4) {
            int nt = (t4 < 2047) ? 4*t4 + 4 : 4*t4;      // clamp: harmless reload
            float nlp0 = lpb[(size_t)(nt+0)*16], nlp1 = lpb[(size_t)(nt+1)*16];
            float nlp2 = lpb[(size_t)(nt+2)*16], nlp3 = lpb[(size_t)(nt+3)*16];
            float nm0 = mb[nt+0], nm1 = mb[nt+1], nm2 = mb[nt+2], nm3 = mb[nt+3];
            fstep(clp0, cm0, true);
            fstep(clp1, cm1, false);
            fstep(clp2, cm2, false);
            fstep(clp3, cm3, false);
            clp0 = nlp0; clp1 = nlp1; clp2 = nlp2; clp3 = nlp3;
            cm0 = nm0; cm1 = nm1; cm2 = nm2; cm3 = nm3;
        }
        float S = ((q[0]+q[1])+(q[2]+q[3])) + ((q[4]+q[5])+(q[6]+q[7]))
                + ((q[8]+q[9])+(q[10]+q[11])) + ((q[12]+q[13])+(q[14]+q[15]));
        double logp = macc + 0.69314718055994530942 * (lacc + (double)log2f(S));
        if (c == 0) outLogp[b] = (float)logp;
    } else {
        // ---- Viterbi in log space (raw lp keeps us numerically close to ref) ----
        float delta = lpb[0] + lpi;
        uint32_t* psib = PSI + (size_t)b*2048*16 + c;

        auto vstep = [&](float lp) -> int {
            float qd[16];
            bcast16(delta, qd);
            float s[16];
#pragma unroll
            for (int j = 0; j < 16; ++j) s[j] = qd[j] + la[j];
            MaxI r = argmax16(s);
            delta = r.v + lp;
            return r.i;
        };

        int a1 = vstep(lpb[1*16]);
        int a2 = vstep(lpb[2*16]);
        int a3 = vstep(lpb[3*16]);
        psib[0] = ((uint32_t)a1 << 8) | ((uint32_t)a2 << 16) | ((uint32_t)a3 << 24);

        float clp0 = lpb[4*16], clp1 = lpb[5*16], clp2 = lpb[6*16], clp3 = lpb[7*16];
        for (int t4 = 1; t4 < 2048; ++t4) {
            int nt = (t4 < 2047) ? 4*t4 + 4 : 4*t4;
            float nlp0 = lpb[(size_t)(nt+0)*16], nlp1 = lpb[(size_t)(nt+1)*16];
            float nlp2 = lpb[(size_t)(nt+2)*16], nlp3 = lpb[(size_t)(nt+3)*16];
            int b0 = vstep(clp0);
            int b1 = vstep(clp1);
            int b2 = vstep(clp2);
            int b3 = vstep(clp3);
            psib[(size_t)t4*16] = (uint32_t)b0 | ((uint32_t)b1 << 8)
                                | ((uint32_t)b2 << 16) | ((uint32_t)b3 << 24);
            clp0 = nlp0; clp1 = nlp1; clp2 = nlp2; clp3 = nlp3;
        }
        // last-state argmax (first occurrence on ties)
        float qd[16];
        bcast16(delta, qd);
        MaxI r = argmax16(qd);
        if (c == 0) CL[b] = r.i;
    }
}

// ---------------------------------------------------------------------------
// Backtrace via pointer jumping.  F_k(c) = psi_{k+1}[c];  c[k] = F_k(c[k+1]).
// btA: compose each 128-step block's map G_i (parallel).
// btB: chain block boundaries (single small block).
// btC: refill within blocks and write c_est.
// ---------------------------------------------------------------------------
__global__ __launch_bounds__(64) void k_btA(const uint32_t* __restrict__ PSI,
                                            uint8_t* __restrict__ G)
{
    const int tid = threadIdx.x, gl = tid >> 4, c = tid & 15;
    const int gid = blockIdx.x*4 + gl;
    const int b = gid >> 6, i = gid & 63;
    __shared__ uint32_t lds[4][33][16];
    const uint32_t* psib = PSI + (size_t)b*2048*16;
    for (int s = 0; s < 33; ++s) {
        int t4 = 32*i + s; if (t4 > 2047) t4 = 2047;
        lds[gl][s][c] = psib[(size_t)t4*16 + c];
    }
    __syncthreads();
    const int lo = 128*i;
    const int hi = (i == 63) ? 8190 : lo + 127;
    int gg = c;
    for (int k = hi; k >= lo; --k) {
        int t = k + 1;
        uint32_t w = lds[gl][(t >> 2) - 32*i][gg];
        gg = (w >> ((t & 3)*8)) & 15;
    }
    G[((size_t)b*64 + i)*16 + c] = (uint8_t)gg;
}

__global__ __launch_bounds__(64) void k_btB(const uint8_t* __restrict__ G,
                                            const int* __restrict__ CL,
                                            uint8_t* __restrict__ BD)
{
    __shared__ uint8_t gl[64*64*16];   // 64 KiB
    const int tid = threadIdx.x;
    const uint4* src = (const uint4*)G;
    uint4* dst = (uint4*)gl;
    for (int k = 0; k < 64; ++k) dst[tid + 64*k] = src[tid + 64*k];
    __syncthreads();
    int b = tid;
    int e = CL[b];
    for (int i = 63; i >= 0; --i) {
        e = gl[((b*64) + i)*16 + e];
        BD[b*64 + i] = (uint8_t)e;
    }
}

__global__ __launch_bounds__(64) void k_btC(const uint32_t* __restrict__ PSI,
                                            const uint8_t* __restrict__ BD,
                                            const int* __restrict__ CL,
                                            float* __restrict__ oc)
{
    const int tid = threadIdx.x, gl = tid >> 4, c = tid & 15;
    const int gid = blockIdx.x*4 + gl;
    const int b = gid >> 6, i = gid & 63;
    __shared__ uint32_t lds[4][33][16];
    const uint32_t* psib = PSI + (size_t)b*2048*16;
    for (int s = 0; s < 33; ++s) {
        int t4 = 32*i + s; if (t4 > 2047) t4 = 2047;
        lds[gl][s][c] = psib[(size_t)t4*16 + c];
    }
    __syncthreads();
    const int lo = 128*i;
    const int hi = (i == 63) ? 8190 : lo + 127;
    int cn = (i == 63) ? CL[b] : (int)BD[b*64 + i + 1];
    float* ob = oc + (size_t)b*TT;
    if (i == 63 && c == 0) ob[8191] = (float)cn;
    for (int k = hi; k >= lo; --k) {
        int t = k + 1;
        uint32_t w = lds[gl][(t >> 2) - 32*i][cn];
        cn = (w >> ((t & 3)*8)) & 15;
        if (c == 0) ob[k] = (float)cn;
    }
}

// ---------------------------------------------------------------------------
// ws layout: [0,8M) PSI dwords | [8M,40M) LP | [40M,42M) M | [42M,..) G,BD,CL
// total ~42.1 MiB
// ---------------------------------------------------------------------------
extern "C" void kernel_launch(void* const* d_in, const int* in_sizes, int n_in,
                              void* d_out, int out_size, void* d_ws, size_t ws_size,
                              hipStream_t stream)
{
    (void)in_sizes; (void)n_in; (void)out_size; (void)ws_size;
    const float* x    = (const float*)d_in[0];
    const float* mug  = (const float*)d_in[1];
    const float* sdg  = (const float*)d_in[2];
    const float* lAg  = (const float*)d_in[3];
    const float* lpig = (const float*)d_in[4];
    float* out = (float*)d_out;

    uint8_t* ws = (uint8_t*)d_ws;
    uint32_t* PSI = (uint32_t*)(ws + 0);
    float* LP = (float*)(ws + (8ull << 20));
    float* M  = (float*)(ws + (40ull << 20));
    uint8_t* G  = ws + (42ull << 20);
    uint8_t* BD = G + 64*64*16;
    int* CL = (int*)(BD + 64*64);

    hipLaunchKernelGGL(k_emis, dim3(BB*TT/16), dim3(256), 0, stream, x, mug, sdg, LP, M);
    hipLaunchKernelGGL(k_chain, dim3(32), dim3(64), 0, stream, lAg, lpig, LP, M, out, PSI, CL);
    hipLaunchKernelGGL(k_btA, dim3(BB*NBK/4), dim3(64), 0, stream, PSI, G);
    hipLaunchKernelGGL(k_btB, dim3(1), dim3(64), 0, stream, G, CL, BD);
    hipLaunchKernelGGL(k_btC, dim3(BB*NBK/4), dim3(64), 0, stream, PSI, BD, CL, out + BB);
}